// Round 1
// baseline (1115.778 us; speedup 1.0000x reference)
//
#include <hip/hip_runtime.h>
#include <math.h>

#define BB 512
#define TT 1024
#define LL 48

__device__ __forceinline__ float readlane_f(float v, int lane) {
    return __int_as_float(__builtin_amdgcn_readlane(__float_as_int(v), lane));
}

__global__ __launch_bounds__(64) void viterbi_kernel(
    const float* __restrict__ emissions,   // [B,T,L]
    const float* __restrict__ transitions, // [L,L]
    const float* __restrict__ start_tr,    // [L]
    const float* __restrict__ end_tr,      // [L]
    int* __restrict__ out)                 // [B,T] int32
{
    __shared__ unsigned char bp[(TT - 1) * LL];  // 49,104 B backpointers

    const int b = blockIdx.x;
    const int j = threadIdx.x;            // lane = tag
    const bool active = (j < LL);

    // Transition column j in registers: tc[i] = transitions[i][j]
    float tc[LL];
#pragma unroll
    for (int i = 0; i < LL; ++i)
        tc[i] = active ? transitions[i * LL + j] : 0.0f;

    const float* em = emissions + (size_t)b * TT * LL;

    // v0 = start + emissions[:,0]
    float v = active ? (start_tr[j] + em[j]) : -INFINITY;

    // prefetch t=1 emission
    float e_next = active ? em[LL + j] : 0.0f;

    for (int t = 1; t < TT; ++t) {
        float e = e_next;
        int tn = (t + 1 < TT) ? (t + 1) : (TT - 1);
        e_next = active ? em[tn * LL + j] : 0.0f;   // prefetch (dead last iter)

        // best over previous tag i of v[i] + trans[i][j]
        float best = readlane_f(v, 0) + tc[0];
        int arg = 0;
#pragma unroll
        for (int i = 1; i < LL; ++i) {
            float s = readlane_f(v, i) + tc[i];
            if (s > best) { best = s; arg = i; }   // strict > keeps first-max (jnp.argmax)
        }
        v = best + e;
        if (active) bp[(t - 1) * LL + j] = (unsigned char)arg;
    }

    // end transitions + final argmax across tags
    if (active) v += end_tr[j];

    float bestv = readlane_f(v, 0);
    int tag = 0;
#pragma unroll
    for (int i = 1; i < LL; ++i) {
        float s = readlane_f(v, i);
        if (s > bestv) { bestv = s; tag = i; }
    }

    int* ob = out + (size_t)b * TT;
    if (j == 0) ob[TT - 1] = tag;

    // Backtrack: tag_r = bp[r][tag_{r+1}], r = T-2 .. 0.
    // Chunked: 32 independent coalesced ds_read_u8 row loads, then a chain of
    // cheap readlane selects (dependency only on the select, not the load).
    __syncthreads();  // bp writes visible (single wave, but cheap + safe)

    for (int hi = TT - 2; hi >= 0; hi -= 32) {
        int lo = hi - 31; if (lo < 0) lo = 0;
        int n = hi - lo + 1;

        unsigned int row[32];
#pragma unroll
        for (int k = 0; k < 32; ++k) {
            row[k] = 0;
            if (k < n && active)
                row[k] = (unsigned int)bp[(lo + k) * LL + j];
        }
#pragma unroll
        for (int k = 31; k >= 0; --k) {
            if (k < n) {
                tag = __builtin_amdgcn_readlane((int)row[k], tag);
                if (j == 0) ob[lo + k] = tag;
            }
        }
    }
}

extern "C" void kernel_launch(void* const* d_in, const int* in_sizes, int n_in,
                              void* d_out, int out_size, void* d_ws, size_t ws_size,
                              hipStream_t stream) {
    const float* emissions   = (const float*)d_in[0];
    // d_in[1] = mask — unused by the reference decode body
    const float* transitions = (const float*)d_in[2];
    const float* start_tr    = (const float*)d_in[3];
    const float* end_tr      = (const float*)d_in[4];
    int* out = (int*)d_out;

    viterbi_kernel<<<dim3(BB), dim3(64), 0, stream>>>(
        emissions, transitions, start_tr, end_tr, out);
}

// Round 2
// 1042.711 us; speedup vs baseline: 1.0701x; 1.0701x over previous
//
#include <hip/hip_runtime.h>
#include <math.h>

#define BB 512
#define TT 1024
#define LL 48

__device__ __forceinline__ float readlane_f(float v, int lane) {
    return __int_as_float(__builtin_amdgcn_readlane(__float_as_int(v), lane));
}

// Tournament argmax over s[0..47] with first-max (smallest index) tie-break.
// Left subtree always holds smaller indices; switch to right only on strict >.
__device__ __forceinline__ void argmax48(const float* s, float& bestv, int& besti) {
    float val[24];
    int   idx[24];
#pragma unroll
    for (int k = 0; k < 24; ++k) {
        bool c = s[2 * k + 1] > s[2 * k];
        val[k] = c ? s[2 * k + 1] : s[2 * k];
        idx[k] = c ? 2 * k + 1 : 2 * k;
    }
#pragma unroll
    for (int k = 0; k < 12; ++k) {
        bool c = val[2 * k + 1] > val[2 * k];
        val[k] = c ? val[2 * k + 1] : val[2 * k];
        idx[k] = c ? idx[2 * k + 1] : idx[2 * k];
    }
#pragma unroll
    for (int k = 0; k < 6; ++k) {
        bool c = val[2 * k + 1] > val[2 * k];
        val[k] = c ? val[2 * k + 1] : val[2 * k];
        idx[k] = c ? idx[2 * k + 1] : idx[2 * k];
    }
#pragma unroll
    for (int k = 0; k < 3; ++k) {
        bool c = val[2 * k + 1] > val[2 * k];
        val[k] = c ? val[2 * k + 1] : val[2 * k];
        idx[k] = c ? idx[2 * k + 1] : idx[2 * k];
    }
    bool c01 = val[1] > val[0];
    float bv = c01 ? val[1] : val[0];
    int   bi = c01 ? idx[1] : idx[0];
    bool c2 = val[2] > bv;
    bestv = c2 ? val[2] : bv;
    besti = c2 ? idx[2] : bi;
}

__global__ __launch_bounds__(64) void viterbi_kernel(
    const float* __restrict__ emissions,   // [B,T,L]
    const float* __restrict__ transitions, // [L,L]
    const float* __restrict__ start_tr,    // [L]
    const float* __restrict__ end_tr,      // [L]
    int* __restrict__ out)                 // [B,T] int32
{
    __shared__ unsigned char bp[(TT - 1) * LL];  // 49,104 B backpointers

    const int b = blockIdx.x;
    const int j = threadIdx.x;            // lane = tag
    const bool active = (j < LL);

    // Transition column j in registers: tc[i] = transitions[i][j]
    float tc[LL];
#pragma unroll
    for (int i = 0; i < LL; ++i)
        tc[i] = active ? transitions[i * LL + j] : 0.0f;

    const float* em = emissions + (size_t)b * TT * LL;

    // v0 = start + emissions[:,0]
    float v = active ? (start_tr[j] + em[j]) : -INFINITY;

    // prefetch t=1 emission
    float e_next = active ? em[LL + j] : 0.0f;

    for (int t = 1; t < TT; ++t) {
        float e = e_next;
        int tn = (t + 1 < TT) ? (t + 1) : (TT - 1);
        e_next = active ? em[tn * LL + j] : 0.0f;   // prefetch (dead last iter)

        // s[i] = v[i] + trans[i][j] — broadcast via readlane (independent ops)
        float s[LL];
#pragma unroll
        for (int i = 0; i < LL; ++i)
            s[i] = readlane_f(v, i) + tc[i];

        float best; int arg;
        argmax48(s, best, arg);

        v = best + e;
        if (active) bp[(t - 1) * LL + j] = (unsigned char)arg;
    }

    // end transitions + final argmax across tags
    if (active) v += end_tr[j];

    float sf[LL];
#pragma unroll
    for (int i = 0; i < LL; ++i)
        sf[i] = readlane_f(v, i);

    float bestv; int tag;
    argmax48(sf, bestv, tag);

    int* ob = out + (size_t)b * TT;
    if (j == 0) ob[TT - 1] = tag;

    // Backtrack: tag_r = bp[r][tag_{r+1}], r = T-2 .. 0.
    // Chunked: 32 independent coalesced ds_read_u8 row loads, then a chain of
    // cheap readlane selects (dependency only on the select, not the load).
    __syncthreads();  // bp writes visible (single wave, but cheap + safe)

    for (int hi = TT - 2; hi >= 0; hi -= 32) {
        int lo = hi - 31; if (lo < 0) lo = 0;
        int n = hi - lo + 1;

        unsigned int row[32];
#pragma unroll
        for (int k = 0; k < 32; ++k) {
            row[k] = 0;
            if (k < n && active)
                row[k] = (unsigned int)bp[(lo + k) * LL + j];
        }
#pragma unroll
        for (int k = 31; k >= 0; --k) {
            if (k < n) {
                tag = __builtin_amdgcn_readlane((int)row[k], tag);
                if (j == 0) ob[lo + k] = tag;
            }
        }
    }
}

extern "C" void kernel_launch(void* const* d_in, const int* in_sizes, int n_in,
                              void* d_out, int out_size, void* d_ws, size_t ws_size,
                              hipStream_t stream) {
    const float* emissions   = (const float*)d_in[0];
    // d_in[1] = mask — unused by the reference decode body
    const float* transitions = (const float*)d_in[2];
    const float* start_tr    = (const float*)d_in[3];
    const float* end_tr      = (const float*)d_in[4];
    int* out = (int*)d_out;

    viterbi_kernel<<<dim3(BB), dim3(64), 0, stream>>>(
        emissions, transitions, start_tr, end_tr, out);
}

// Round 4
// 582.353 us; speedup vs baseline: 1.9160x; 1.7905x over previous
//
#include <hip/hip_runtime.h>
#include <math.h>

#define BB 512
#define TT 1024
#define LL 48

__device__ __forceinline__ float readlane_f(float v, int lane) {
    return __int_as_float(__builtin_amdgcn_readlane(__float_as_int(v), lane));
}

// Tournament argmax over s[0..47] with first-max (smallest index) tie-break.
// Left subtree always holds smaller indices; switch to right only on strict >.
__device__ __forceinline__ void argmax48(const float* s, float& bestv, int& besti) {
    float val[24];
    int   idx[24];
#pragma unroll
    for (int k = 0; k < 24; ++k) {
        bool c = s[2 * k + 1] > s[2 * k];
        val[k] = c ? s[2 * k + 1] : s[2 * k];
        idx[k] = c ? 2 * k + 1 : 2 * k;
    }
#pragma unroll
    for (int k = 0; k < 12; ++k) {
        bool c = val[2 * k + 1] > val[2 * k];
        val[k] = c ? val[2 * k + 1] : val[2 * k];
        idx[k] = c ? idx[2 * k + 1] : idx[2 * k];
    }
#pragma unroll
    for (int k = 0; k < 6; ++k) {
        bool c = val[2 * k + 1] > val[2 * k];
        val[k] = c ? val[2 * k + 1] : val[2 * k];
        idx[k] = c ? idx[2 * k + 1] : idx[2 * k];
    }
#pragma unroll
    for (int k = 0; k < 3; ++k) {
        bool c = val[2 * k + 1] > val[2 * k];
        val[k] = c ? val[2 * k + 1] : val[2 * k];
        idx[k] = c ? idx[2 * k + 1] : idx[2 * k];
    }
    bool c01 = val[1] > val[0];
    float bv = c01 ? val[1] : val[0];
    int   bi = c01 ? idx[1] : idx[0];
    bool c2 = val[2] > bv;
    bestv = c2 ? val[2] : bv;
    besti = c2 ? idx[2] : bi;
}

__global__ __launch_bounds__(64) void viterbi_kernel(
    const float* __restrict__ emissions,   // [B,T,L]
    const float* __restrict__ transitions, // [L,L]
    const float* __restrict__ start_tr,    // [L]
    const float* __restrict__ end_tr,      // [L]
    int* __restrict__ out)                 // [B,T] int32
{
    __shared__ unsigned char bp[(TT - 1) * LL];  // 49,104 B backpointers

    const int b = blockIdx.x;
    const int j = threadIdx.x;
    const int jc = (j < LL) ? j : (LL - 1);   // lanes 48-63 mirror lane 47: branch-free

    // Transition column jc in registers: tc[i] = transitions[i][jc]
    float tc[LL];
#pragma unroll
    for (int i = 0; i < LL; ++i)
        tc[i] = transitions[i * LL + jc];

    const float* em = emissions + (size_t)b * TT * LL;

    // v0 = start + emissions[:,0]
    float v = start_tr[jc] + em[jc];

    // 3-deep emission pipeline: e1 consumed at step t, e2 at t+1, e3 issued for t+2.
    // Two loads always in flight -> waitcnt at vmcnt(2), latency fully hidden.
    float e1 = em[1 * LL + jc];
    float e2 = em[2 * LL + jc];

#pragma unroll 3
    for (int t = 1; t < TT; ++t) {
        int tn = t + 2; if (tn >= TT) tn = TT - 1;
        float e3 = em[(size_t)tn * LL + jc];   // prefetch, 2 iterations ahead

        // s[i] = v[i] + trans[i][jc] — broadcast via readlane (independent ops)
        float s[LL];
#pragma unroll
        for (int i = 0; i < LL; ++i)
            s[i] = readlane_f(v, i) + tc[i];

        float best; int arg;
        argmax48(s, best, arg);

        v = best + e1;
        bp[(t - 1) * LL + jc] = (unsigned char)arg;  // lanes 48-63 write lane-47's value/addr

        e1 = e2; e2 = e3;   // renamed away by unroll
    }

    // end transitions + final argmax across tags
    v += end_tr[jc];

    float sf[LL];
#pragma unroll
    for (int i = 0; i < LL; ++i)
        sf[i] = readlane_f(v, i);

    float bestv; int tag;
    argmax48(sf, bestv, tag);   // tag is wave-uniform

    int* ob = out + (size_t)b * TT;
    if (j == 0) ob[TT - 1] = tag;

    __syncthreads();  // bp writes -> reads ordering (single wave; cheap insurance)

    // Backtrack: tag_r = bp[r][tag_{r+1}], r = T-2 .. 0.
    // 32 coalesced row loads (independent), then a chain of cheap readlane
    // selects; scatter each uniform tag into lane k via cndmask (tag is SGPR,
    // so (j==k)?tag:outv is a single v_cndmask_b32) -> 1 coalesced store.
    for (int hi = TT - 2; hi >= 0; hi -= 32) {
        int lo = hi - 31; if (lo < 0) lo = 0;
        int n = hi - lo + 1;

        unsigned int row[32];
#pragma unroll
        for (int k = 0; k < 32; ++k)
            row[k] = (unsigned int)bp[(lo + k) * LL + jc];  // always-valid addr

        int outv = 0;
#pragma unroll
        for (int k = 31; k >= 0; --k) {
            if (k < n) {
                tag = __builtin_amdgcn_readlane((int)row[k], tag);
                outv = (j == k) ? tag : outv;   // v_cndmask: lane k keeps uniform tag
            }
        }
        if (j < n) ob[lo + j] = outv;   // one coalesced store per chunk
    }
}

extern "C" void kernel_launch(void* const* d_in, const int* in_sizes, int n_in,
                              void* d_out, int out_size, void* d_ws, size_t ws_size,
                              hipStream_t stream) {
    const float* emissions   = (const float*)d_in[0];
    // d_in[1] = mask — unused by the reference decode body
    const float* transitions = (const float*)d_in[2];
    const float* start_tr    = (const float*)d_in[3];
    const float* end_tr      = (const float*)d_in[4];
    int* out = (int*)d_out;

    viterbi_kernel<<<dim3(BB), dim3(64), 0, stream>>>(
        emissions, transitions, start_tr, end_tr, out);
}